// Round 5
// baseline (274.938 us; speedup 1.0000x reference)
//
#include <hip/hip_runtime.h>

#define HW 36864            // 192*192
#define HDIM 192
#define NUNITS 8192         // 1024 windows * 8 heads
#define UPB 4               // units per block

typedef __fp16 h2 __attribute__((ext_vector_type(2)));   // matches cvt_pkrtz return type

static __device__ __forceinline__ h2 pk2(float a, float b) {
    return __builtin_amdgcn_cvt_pkrtz(a, b);   // v_cvt_pkrtz_f16_f32
}
static __device__ __forceinline__ unsigned h2u(h2 x) {
    union { h2 h; unsigned u; } c; c.h = x; return c.u;
}
static __device__ __forceinline__ h2 u2h(unsigned x) {
    union { unsigned u; h2 h; } c; c.u = x; return c.h;
}

// 24-elem dot via v_dot2_f32_f16, 4 independent 3-deep chains
static __device__ __forceinline__ float rowdot(const uint4* kk, const h2* qh) {
    float d0 = __builtin_amdgcn_fdot2(u2h(kk[0].x), qh[0], 0.f, false);
    float d1 = __builtin_amdgcn_fdot2(u2h(kk[0].y), qh[1], 0.f, false);
    float d2 = __builtin_amdgcn_fdot2(u2h(kk[0].z), qh[2], 0.f, false);
    float d3 = __builtin_amdgcn_fdot2(u2h(kk[0].w), qh[3], 0.f, false);
    d0 = __builtin_amdgcn_fdot2(u2h(kk[1].x), qh[4],  d0, false);
    d1 = __builtin_amdgcn_fdot2(u2h(kk[1].y), qh[5],  d1, false);
    d2 = __builtin_amdgcn_fdot2(u2h(kk[1].z), qh[6],  d2, false);
    d3 = __builtin_amdgcn_fdot2(u2h(kk[1].w), qh[7],  d3, false);
    d0 = __builtin_amdgcn_fdot2(u2h(kk[2].x), qh[8],  d0, false);
    d1 = __builtin_amdgcn_fdot2(u2h(kk[2].y), qh[9],  d1, false);
    d2 = __builtin_amdgcn_fdot2(u2h(kk[2].z), qh[10], d2, false);
    d3 = __builtin_amdgcn_fdot2(u2h(kk[2].w), qh[11], d3, false);
    return (d0 + d1) + (d2 + d3);
}

static __device__ __forceinline__ void rowpv(const uint4* vv, h2 p2, h2* o2) {
    o2[0]  += p2 * u2h(vv[0].x);  o2[1]  += p2 * u2h(vv[0].y);
    o2[2]  += p2 * u2h(vv[0].z);  o2[3]  += p2 * u2h(vv[0].w);
    o2[4]  += p2 * u2h(vv[1].x);  o2[5]  += p2 * u2h(vv[1].y);
    o2[6]  += p2 * u2h(vv[1].z);  o2[7]  += p2 * u2h(vv[1].w);
    o2[8]  += p2 * u2h(vv[2].x);  o2[9]  += p2 * u2h(vv[2].y);
    o2[10] += p2 * u2h(vv[2].z);  o2[11] += p2 * u2h(vv[2].w);
}

__global__ __launch_bounds__(256, 4)
void attn_scatter(const float* __restrict__ x,
                  const float* __restrict__ fc,   // (8,8,2) cos/sin
                  const float* __restrict__ wgt,  // (192,192)
                  float* __restrict__ out)        // (576,192,192) pre-zeroed
{
    const int unit = threadIdx.x >> 6;
    const int lane = threadIdx.x & 63;
    const int gid  = blockIdx.x * UPB + unit;   // 0..8191
    const int head = gid & 7;
    const int wi   = gid >> 3;
    const int g    = wi & 3;
    const int iw   = (wi >> 2) & 15;
    const int ih   = wi >> 6;

    const int r   = lane >> 3;
    const int col = lane & 7;

    __shared__ __align__(16) unsigned kbuf[UPB * 64 * 12];  // f16-pair rows
    __shared__ __align__(16) unsigned vbuf[UPB * 64 * 12];
    __shared__ float frs[64];
    __shared__ float fis[64];   // NOTE: kbuf/vbuf prefetch may overread into these — harmless

    if (threadIdx.x < 64) {
        float2 t = ((const float2*)fc)[threadIdx.x];
        frs[threadIdx.x] = t.x;
        fis[threadIdx.x] = t.y;
    }

    const int h0 = ih * 12 + r;
    const int w0 = iw * 12 + col;
    int in_h = h0 + ((g & 1) ? 6 : 0); if (in_h >= HDIM) in_h = 2 * HDIM - 2 - in_h;
    int in_w = w0 + ((g & 2) ? 6 : 0); if (in_w >= HDIM) in_w = 2 * HDIM - 2 - in_w;

    const float* xb = x + (size_t)(head * 24) * HW + in_h * HDIM + in_w;

    // issue ALL gather loads up-front (72 independent VMEM ops in flight)
    float q[24], k[24], v[24];
#pragma unroll
    for (int dd = 0; dd < 24; ++dd) q[dd] = xb[(size_t)dd * HW];
#pragma unroll
    for (int dd = 0; dd < 24; ++dd) k[dd] = xb[(size_t)dd * HW + (size_t)192 * HW];
#pragma unroll
    for (int dd = 0; dd < 24; ++dd) v[dd] = xb[(size_t)dd * HW + (size_t)384 * HW];

    __syncthreads();  // frs/fis ready

    // positional encoding on q, k (fp32)
#pragma unroll
    for (int p = 0; p < 8; ++p) {
        const float frr = frs[r * 8 + p],   fir = fis[r * 8 + p];
        const float frc = frs[col * 8 + p], fic = fis[col * 8 + p];
        {
            float a = q[3*p], b = q[3*p+1], c3 = q[3*p+2];
            float b2 = a * fir + b * frr;
            q[3*p]   = a * frr - b * fir;
            q[3*p+1] = b2 * frc - c3 * fic;
            q[3*p+2] = b2 * fic + c3 * frc;
        }
        {
            float a = k[3*p], b = k[3*p+1], c3 = k[3*p+2];
            float b2 = a * fir + b * frr;
            k[3*p]   = a * frr - b * fir;
            k[3*p+1] = b2 * frc - c3 * fic;
            k[3*p+2] = b2 * fic + c3 * frc;
        }
    }

    // stage k (post-PE) and v as packed f16 pairs
    {
        unsigned* kw = &kbuf[(unit * 64 + lane) * 12];
        unsigned* vw = &vbuf[(unit * 64 + lane) * 12];
#pragma unroll
        for (int j = 0; j < 12; ++j) {
            kw[j] = h2u(pk2(k[2*j], k[2*j+1]));
            vw[j] = h2u(pk2(v[2*j], v[2*j+1]));
        }
    }

    // q -> f16 pairs, pre-scaled by 1/sqrt(24)
    h2 qh[12];
#pragma unroll
    for (int j = 0; j < 12; ++j)
        qh[j] = pk2(q[2*j] * 0.20412414523193154f, q[2*j+1] * 0.20412414523193154f);

    __syncthreads();

    float sum = 0.f;
    h2 o2[12];
#pragma unroll
    for (int j = 0; j < 12; ++j) { o2[j][0] = (__fp16)0.0f; o2[j][1] = (__fp16)0.0f; }

    const uint4* kb4 = (const uint4*)&kbuf[unit * 64 * 12];  // 3 uint4 per row
    const uint4* vb4 = (const uint4*)&vbuf[unit * 64 * 12];

    // software-pipelined m-loop, explicit double buffer, prefetch distance 2
    uint4 kA[3], vA[3], kB[3], vB[3];
    kA[0] = kb4[0]; kA[1] = kb4[1]; kA[2] = kb4[2];
    vA[0] = vb4[0]; vA[1] = vb4[1]; vA[2] = vb4[2];
    kB[0] = kb4[3]; kB[1] = kb4[4]; kB[2] = kb4[5];
    vB[0] = vb4[3]; vB[1] = vb4[4]; vB[2] = vb4[5];

#pragma unroll 4
    for (int m = 0; m < 64; m += 2) {
        {   // row m (buffer A)
            const float s = rowdot(kA, qh);
            const int pf = (m + 2) * 3;                 // rows 64/65 overread: in-LDS, unused
            kA[0] = kb4[pf]; kA[1] = kb4[pf + 1]; kA[2] = kb4[pf + 2];
            const float p = __expf(s);
            sum += p;
            const h2 p2 = pk2(p, p);
            rowpv(vA, p2, o2);
            vA[0] = vb4[pf]; vA[1] = vb4[pf + 1]; vA[2] = vb4[pf + 2];
        }
        {   // row m+1 (buffer B)
            const float s = rowdot(kB, qh);
            const int pf = (m + 3) * 3;
            kB[0] = kb4[pf]; kB[1] = kb4[pf + 1]; kB[2] = kb4[pf + 2];
            const float p = __expf(s);
            sum += p;
            const h2 p2 = pk2(p, p);
            rowpv(vB, p2, o2);
            vB[0] = vb4[pf]; vB[1] = vb4[pf + 1]; vB[2] = vb4[pf + 2];
        }
    }

    // overlap-add scatter
    const int oh = h0 + ((g & 1) ? 6 : 0);
    const int ow = w0 + ((g & 2) ? 6 : 0);
    if (oh < HDIM && ow < HDIM) {
        const float sc = (1.0f / sum) / wgt[oh * HDIM + ow];
        float* ob = out + (size_t)(head * 24) * HW + oh * HDIM + ow;
#pragma unroll
        for (int j = 0; j < 12; ++j) {
            atomicAdd(&ob[(size_t)(2*j)     * HW], (float)o2[j][0] * sc);
            atomicAdd(&ob[(size_t)(2*j + 1) * HW], (float)o2[j][1] * sc);
        }
    }
}

extern "C" void kernel_launch(void* const* d_in, const int* in_sizes, int n_in,
                              void* d_out, int out_size, void* d_ws, size_t ws_size,
                              hipStream_t stream) {
    const float* x   = (const float*)d_in[0];
    const float* fc  = (const float*)d_in[1];
    const float* wgt = (const float*)d_in[2];
    float* out = (float*)d_out;

    (void)hipMemsetAsync(out, 0, (size_t)out_size * sizeof(float), stream);
    attn_scatter<<<NUNITS / UPB, 256, 0, stream>>>(x, fc, wgt, out);
}